// Round 8
// baseline (161.709 us; speedup 1.0000x reference)
//
#include <hip/hip_runtime.h>
#include <math.h>

#define DD 160
#define HH 192
#define WW 160
#define TW 32          // per-wave tile width (full 32-lane row => 0-conflict LDS)
#define TH 2           // per-wave tile height
#define BH 8           // block tile height (4 waves stacked)
#define TD 8           // slices per block
#define HW (HH * WW)
#define NVOX (DD * HW)
#define HTW 34         // halo cols
#define HTH 4          // halo rows per wave
#define LSTR 34        // row stride: each 32-lane phase covers all 32 banks once
#define HALO (HTH * HTW)   // 136
#define WBUF (HTH * LSTR)  // 136 floats per [wave][parity][field]

// atan via odd minimax poly on [0,1] + rcp range reduction; max err ~1e-5 rad
__device__ __forceinline__ float atan_fast(float r) {
    float ar = fabsf(r);
    float inv = __builtin_amdgcn_rcpf(ar);
    bool big = ar > 1.0f;
    float x = big ? inv : ar;
    float x2 = x * x;
    float p = fmaf(x2, fmaf(x2, fmaf(x2, fmaf(x2, fmaf(x2,
              -0.0117212f, 0.05265332f), -0.11643287f), 0.19354346f),
              -0.33262347f), 0.99997726f);
    p *= x;
    float res = big ? (1.57079632679489662f - p) : p;
    return copysignf(res, r);
}

// 4 independent waves per block, private LDS regions, wave-local distance-1
// pipeline, NO __syncthreads in the main loop. Lane layout is 32-wide rows
// (round-4's empirically zero-conflict geometry: conflicts are per 32-lane
// phase, and each phase here is one row spanning all 32 banks exactly once).
// launch_bounds min-waves=6 caps VGPR at ~85 (round-7 lesson: barrier-free
// full unroll ballooned liveranges to 104 VGPR).
__global__ __launch_bounds__(256, 6) void demons_ori_kernel(
    const float* __restrict__ Mv, const float* __restrict__ Sv,
    const float* __restrict__ flow, float* __restrict__ out)
{
    __shared__ float buf[4][2][2][WBUF];   // [wave][parity][field][h*LSTR+w]
    __shared__ float redbuf[4];

    const int tid = threadIdx.x;
    const int wid = tid >> 6;
    const int lane = tid & 63;
    const int tw = lane & 31;
    const int th = lane >> 5;              // 0..1
    const int w0 = blockIdx.x * TW;
    const int h0 = blockIdx.y * BH + wid * TH;
    const int d0 = blockIdx.z * TD;

    // slice-invariant staging slots: lane, lane+64, lane+128 (136 total)
    const bool has2 = (lane < HALO - 128);   // lanes 0..7
    int gb0, gb1, gb2 = 0;
    bool ok0, ok1, ok2 = false;
    {
        int i = lane;
        int hh = i / HTW, ww = i - HTW * hh;
        int gh = h0 + hh - 1, gw = w0 + ww - 1;
        ok0 = (gh >= 0 && gh < HH && gw >= 0 && gw < WW);
        gb0 = gh * WW + gw;
        i = lane + 64;
        hh = i / HTW; ww = i - HTW * hh;
        gh = h0 + hh - 1; gw = w0 + ww - 1;
        ok1 = (gh >= 0 && gh < HH && gw >= 0 && gw < WW);
        gb1 = gh * WW + gw;
        if (has2) {
            i = lane + 128;
            hh = i / HTW; ww = i - HTW * hh;
            gh = h0 + hh - 1; gw = w0 + ww - 1;
            ok2 = (gh >= 0 && gh < HH && gw >= 0 && gw < WW);
            gb2 = gh * WW + gw;
        }
    }

    // single prefetch set (distance 1) — named scalars only (round-3 lesson)
    float pS0 = 0.f, pM0 = 0.f, pS1 = 0.f, pM1 = 0.f, pS2 = 0.f, pM2 = 0.f;

    auto issue = [&](int d) {
        const bool din = (d >= 0) && (d < DD);
        const size_t base = (size_t)d * HW;
        pS0 = (din && ok0) ? Sv[base + gb0] : 0.f;
        pM0 = (din && ok0) ? Mv[base + gb0] : 0.f;
        pS1 = (din && ok1) ? Sv[base + gb1] : 0.f;
        pM1 = (din && ok1) ? Mv[base + gb1] : 0.f;
        pS2 = (din && ok2) ? Sv[base + gb2] : 0.f;
        pM2 = (din && ok2) ? Mv[base + gb2] : 0.f;
    };
    auto commit = [&](int d) {
        float* __restrict__ bS = &buf[wid][d & 1][0][0];
        float* __restrict__ bM = &buf[wid][d & 1][1][0];
        bS[lane] = pS0;       bM[lane] = pM0;        // banks: all 32 once/phase
        bS[lane + 64] = pS1;  bM[lane + 64] = pM1;
        if (has2) { bS[lane + 128] = pS2; bM[lane + 128] = pM2; }
    };

    const int rb = th * LSTR + tw;   // center voxel at (th+1, tw+1)
    // separable in-plane partials: pq[f] = {Px, Py, B, center}
    auto partials = [&](int par, float pq[2][4]) {
        #pragma unroll
        for (int f = 0; f < 2; ++f) {
            const float* __restrict__ b = &buf[wid][par][f][0];
            const float* r0 = b + rb;
            const float* r1 = r0 + LSTR;
            const float* r2 = r1 + LSTR;
            float v00 = r0[0], v01 = r0[1], v02 = r0[2];
            float v10 = r1[0], v11 = r1[1], v12 = r1[2];
            float v20 = r2[0], v21 = r2[1], v22 = r2[2];
            pq[f][0] = (v02 + 2.f * v12 + v22) - (v00 + 2.f * v10 + v20);
            pq[f][1] = (v20 + 2.f * v21 + v22) - (v00 + 2.f * v01 + v02);
            pq[f][2] = (v00 + v01 + v02) + 2.f * (v10 + v11 + v12)
                     + (v20 + v21 + v22);
            pq[f][3] = v11;
        }
    };

    float Pm[2][4], P0[2][4], Pp[2][4];

    // ---- warmup: distance-1 pipeline fill ----
    issue(d0 - 1);
    commit(d0 - 1);          // only long exposed vmcnt wait of the block
    issue(d0);
    partials((d0 - 1) & 1, Pm);
    commit(d0);              // latency hidden behind partials(Pm)
    issue(d0 + 1);
    partials(d0 & 1, P0);

    const size_t voff0 = (size_t)(h0 + th) * WW + (w0 + tw);
    float fFx = flow[(size_t)d0 * HW + voff0];
    float fFy = flow[(size_t)NVOX + (size_t)d0 * HW + voff0];
    float fFz = flow[2 * (size_t)NVOX + (size_t)d0 * HW + voff0];

    float lsum = 0.f;

    #pragma unroll 2
    for (int dd = 0; dd < TD; ++dd) {
        const int d = d0 + dd;
        commit(d + 1);       // vmcnt wait for loads issued one stage ago
        float nFx = 0.f, nFy = 0.f, nFz = 0.f;
        if (dd < TD - 1) {
            issue(d + 2);    // in flight across this whole stage
            size_t foff = (size_t)(d + 1) * HW + voff0;
            nFx = flow[foff];
            nFy = flow[(size_t)NVOX + foff];
            nFz = flow[2 * (size_t)NVOX + foff];
        }
        partials((d + 1) & 1, Pp);

        float idf = P0[1][3] - P0[0][3];
        float i2 = idf * idf + 1e-10f;
        float gxS = Pm[0][0] + P0[0][0] + Pp[0][0];
        float gyS = Pm[0][1] + P0[0][1] + Pp[0][1];
        float gzS = Pp[0][2] - Pm[0][2];
        float gxM = Pm[1][0] + P0[1][0] + Pp[1][0];
        float gyM = Pm[1][1] + P0[1][1] + Pp[1][1];
        float gzM = Pp[1][2] - Pm[1][2];
        float denS = gxS * gxS + gyS * gyS + gzS * gzS + i2;
        float denM = gxM * gxM + gyM * gyM + gzM * gzM + i2;
        float rS = __builtin_amdgcn_rcpf(denS);
        float rM = __builtin_amdgcn_rcpf(denM);
        float Ux = idf * (gxS * rS + gxM * rM);
        float Uy = idf * (gyS * rS + gyM * rM);
        float Uz = idf * (gzS * rS + gzM * rM);
        float rz = __builtin_amdgcn_rcpf(Uz + 1e-10f);
        float dxz = atan_fast(Ux * rz);
        float dyz = atan_fast(Uy * rz);

        float rf = __builtin_amdgcn_rcpf(fFz + 1e-10f);
        float fxz = atan_fast(fFx * rf);
        float fyz = atan_fast(fFy * rf);

        float e1 = fxz - dxz;
        float e2 = fyz - dyz;
        lsum += e1 * e1 + e2 * e2;

        #pragma unroll
        for (int f = 0; f < 2; ++f)
            #pragma unroll
            for (int q = 0; q < 4; ++q) {
                Pm[f][q] = P0[f][q];
                P0[f][q] = Pp[f][q];
            }
        fFx = nFx; fFy = nFy; fFz = nFz;
    }

    // wave shuffle reduce -> per-wave LDS slot -> one atomic per block
    #pragma unroll
    for (int o = 32; o > 0; o >>= 1)
        lsum += __shfl_down(lsum, o, 64);
    if (lane == 0)
        redbuf[wid] = lsum;
    __syncthreads();
    if (tid == 0) {
        float s = redbuf[0] + redbuf[1] + redbuf[2] + redbuf[3];
        atomicAdd(out, s * (1.0f / (float)NVOX));
    }
}

extern "C" void kernel_launch(void* const* d_in, const int* in_sizes, int n_in,
                              void* d_out, int out_size, void* d_ws, size_t ws_size,
                              hipStream_t stream) {
    const float* Mv   = (const float*)d_in[0];
    const float* Sv   = (const float*)d_in[1];
    const float* flow = (const float*)d_in[2];
    float* out = (float*)d_out;

    hipMemsetAsync(out, 0, sizeof(float), stream);

    dim3 grid(WW / TW, HH / BH, DD / TD);   // 5 x 24 x 20 = 2400 blocks
    demons_ori_kernel<<<grid, dim3(256), 0, stream>>>(Mv, Sv, flow, out);
}

// Round 9
// 129.143 us; speedup vs baseline: 1.2522x; 1.2522x over previous
//
#include <hip/hip_runtime.h>
#include <math.h>

#define DD 160
#define HH 192
#define WW 160
#define TW 32          // block tile width  (full 32-lane rows => 0-conflict LDS)
#define THB 16         // block tile height (4 waves x 2 rows x 2 voxels)
#define TD 8           // slices per block
#define HW (HH * WW)
#define NVOX (DD * HW)
#define HTW 34         // halo cols
#define HTH 18         // halo rows
#define LSTR 34        // row stride: each 32-lane phase = one row = all 32 banks once
#define HALO (HTH * HTW)   // 612

typedef float v2f __attribute__((ext_vector_type(2)));

__device__ __forceinline__ v2f vrcp(v2f a) {
    v2f r;
    r.x = __builtin_amdgcn_rcpf(a.x);
    r.y = __builtin_amdgcn_rcpf(a.y);
    return r;
}

// packed atan: odd minimax poly on [0,1] + rcp range reduction; err ~1e-5 rad.
// x = min(ar, 1/ar) replaces cmp+select (valid since ar >= 0).
__device__ __forceinline__ v2f atanv(v2f r) {
    v2f ar = __builtin_elementwise_abs(r);
    v2f inv = vrcp(ar);
    v2f x = __builtin_elementwise_min(ar, inv);
    v2f x2 = x * x;
    v2f p = __builtin_elementwise_fma(x2,
            __builtin_elementwise_fma(x2,
            __builtin_elementwise_fma(x2,
            __builtin_elementwise_fma(x2,
            __builtin_elementwise_fma(x2, (v2f)(-0.0117212f), (v2f)(0.05265332f)),
            (v2f)(-0.11643287f)), (v2f)(0.19354346f)), (v2f)(-0.33262347f)),
            (v2f)(0.99997726f));
    p *= x;
    v2f q = 1.57079632679489662f - p;
    v2f res;
    res.x = ar.x > 1.0f ? q.x : p.x;
    res.y = ar.y > 1.0f ? q.y : p.y;
    res.x = copysignf(res.x, r.x);
    res.y = copysignf(res.y, r.y);
    return res;
}

// R4 structure (one barrier/stage, distance-1 named-scalar prefetch, 32-wide
// zero-conflict rows) + 2 h-adjacent voxels per thread computed as packed
// fp32 (v_pk_* on gfx950). NO min-waves cap (R8 lesson: forcing VGPR caused
// 14 MB of scratch spill).
__global__ __launch_bounds__(256) void demons_ori_kernel(
    const float* __restrict__ Mv, const float* __restrict__ Sv,
    const float* __restrict__ flow, float* __restrict__ out)
{
    __shared__ float buf[2][2][HTH * LSTR];   // [parity][field][h*LSTR+w]
    __shared__ float redbuf[4];

    const int tid = threadIdx.x;
    const int lane = tid & 63;
    const int wid = tid >> 6;
    const int tw = lane & 31;
    const int r  = wid * 4 + (lane >> 5) * 2;   // thread's first voxel row 0..15
    const int w0 = blockIdx.x * TW;
    const int h0 = blockIdx.y * THB;
    const int d0 = blockIdx.z * TD;

    // slice-invariant staging slots: tid, tid+256, tid+512 (612 total)
    const bool has2 = (tid < HALO - 512);   // tids 0..99
    int gb0, gb1, gb2 = 0;
    bool ok0, ok1, ok2 = false;
    {
        int i = tid;
        int hh = i / HTW, ww = i - HTW * hh;
        int gh = h0 + hh - 1, gw = w0 + ww - 1;
        ok0 = (gh >= 0 && gh < HH && gw >= 0 && gw < WW);
        gb0 = gh * WW + gw;
        i = tid + 256;
        hh = i / HTW; ww = i - HTW * hh;
        gh = h0 + hh - 1; gw = w0 + ww - 1;
        ok1 = (gh >= 0 && gh < HH && gw >= 0 && gw < WW);
        gb1 = gh * WW + gw;
        if (has2) {
            i = tid + 512;
            hh = i / HTW; ww = i - HTW * hh;
            gh = h0 + hh - 1; gw = w0 + ww - 1;
            ok2 = (gh >= 0 && gh < HH && gw >= 0 && gw < WW);
            gb2 = gh * WW + gw;
        }
    }

    // distance-1 prefetch set — named scalars only (round-3 lesson)
    float pS0 = 0.f, pM0 = 0.f, pS1 = 0.f, pM1 = 0.f, pS2 = 0.f, pM2 = 0.f;

    auto issue = [&](int d) {
        const bool din = (d >= 0) && (d < DD);
        const size_t base = (size_t)d * HW;
        pS0 = (din && ok0) ? Sv[base + gb0] : 0.f;
        pM0 = (din && ok0) ? Mv[base + gb0] : 0.f;
        pS1 = (din && ok1) ? Sv[base + gb1] : 0.f;
        pM1 = (din && ok1) ? Mv[base + gb1] : 0.f;
        pS2 = (din && ok2) ? Sv[base + gb2] : 0.f;
        pM2 = (din && ok2) ? Mv[base + gb2] : 0.f;
    };
    auto commit = [&](int d) {
        float* __restrict__ bS = &buf[d & 1][0][0];
        float* __restrict__ bM = &buf[d & 1][1][0];
        bS[tid] = pS0;        bM[tid] = pM0;
        bS[tid + 256] = pS1;  bM[tid + 256] = pM1;
        if (has2) { bS[tid + 512] = pS2; bM[tid + 512] = pM2; }
    };

    const int rb = r * LSTR + tw;   // stencil window rows r..r+3, cols tw..tw+2
    // separable in-plane partials for the 2-voxel pair; row sums shared.
    auto fieldPartials = [&](const float* __restrict__ b,
                             v2f& Px, v2f& Py, v2f& Bq, v2f& Cq) {
        const float* r0 = b + rb;
        const float* r1 = r0 + LSTR;
        const float* r2 = r1 + LSTR;
        const float* r3 = r2 + LSTR;
        float a0 = r0[0], b0 = r0[1], c0 = r0[2];
        float a1 = r1[0], b1 = r1[1], c1 = r1[2];
        float a2 = r2[0], b2 = r2[1], c2 = r2[2];
        float a3 = r3[0], b3 = r3[1], c3 = r3[2];
        float X0 = c0 - a0, X1 = c1 - a1, X2 = c2 - a2, X3 = c3 - a3;
        float W0 = a0 + 2.f * b0 + c0, W1 = a1 + 2.f * b1 + c1;
        float W2 = a2 + 2.f * b2 + c2, W3 = a3 + 2.f * b3 + c3;
        float I0 = a0 + b0 + c0, I1 = a1 + b1 + c1;
        float I2 = a2 + b2 + c2, I3 = a3 + b3 + c3;
        Px = (v2f){X0 + 2.f * X1 + X2, X1 + 2.f * X2 + X3};
        Py = (v2f){W2 - W0, W3 - W1};
        Bq = (v2f){I0 + 2.f * I1 + I2, I1 + 2.f * I2 + I3};
        Cq = (v2f){b1, b2};
    };

    // register ring: named v2f per slice {m,z,p} x field {S,M} x {Px,Py,B,C}
    v2f mSPx, mSPy, mSB, mSC, mMPx, mMPy, mMB, mMC;
    v2f zSPx, zSPy, zSB, zSC, zMPx, zMPy, zMB, zMC;
    v2f pSPx, pSPy, pSB, pSC, pMPx, pMPy, pMB, pMC;

    // ---- warmup (R4 sequence) ----
    issue(d0 - 1);
    commit(d0 - 1);          // only long exposed vmcnt wait of the block
    issue(d0);
    __syncthreads();
    fieldPartials(&buf[(d0 - 1) & 1][0][0], mSPx, mSPy, mSB, mSC);
    fieldPartials(&buf[(d0 - 1) & 1][1][0], mMPx, mMPy, mMB, mMC);
    commit(d0);
    issue(d0 + 1);
    __syncthreads();
    fieldPartials(&buf[d0 & 1][0][0], zSPx, zSPy, zSB, zSC);
    fieldPartials(&buf[d0 & 1][1][0], zMPx, zMPy, zMB, zMC);

    const size_t voffA = (size_t)(h0 + r) * WW + (w0 + tw);   // voxel A; B = +WW
    v2f fFx, fFy, fFz;
    {
        size_t o = (size_t)d0 * HW + voffA;
        fFx = (v2f){flow[o], flow[o + WW]};
        fFy = (v2f){flow[NVOX + o], flow[NVOX + o + WW]};
        fFz = (v2f){flow[2 * (size_t)NVOX + o], flow[2 * (size_t)NVOX + o + WW]};
    }

    v2f vsum = (v2f){0.f, 0.f};

    #pragma unroll
    for (int dd = 0; dd < TD; ++dd) {
        const int d = d0 + dd;
        commit(d + 1);       // vmcnt wait for loads issued one stage ago
        v2f nFx = (v2f){0.f, 0.f}, nFy = nFx, nFz = nFx;
        if (dd < TD - 1) {
            issue(d + 2);    // in flight across this whole stage
            size_t o = (size_t)(d + 1) * HW + voffA;
            nFx = (v2f){flow[o], flow[o + WW]};
            nFy = (v2f){flow[NVOX + o], flow[NVOX + o + WW]};
            nFz = (v2f){flow[2 * (size_t)NVOX + o], flow[2 * (size_t)NVOX + o + WW]};
        }
        __syncthreads();
        fieldPartials(&buf[(d + 1) & 1][0][0], pSPx, pSPy, pSB, pSC);
        fieldPartials(&buf[(d + 1) & 1][1][0], pMPx, pMPy, pMB, pMC);

        v2f idf = zMC - zSC;
        v2f i2  = __builtin_elementwise_fma(idf, idf, (v2f)(1e-10f));
        v2f gxS = mSPx + zSPx + pSPx;
        v2f gyS = mSPy + zSPy + pSPy;
        v2f gzS = pSB - mSB;
        v2f gxM = mMPx + zMPx + pMPx;
        v2f gyM = mMPy + zMPy + pMPy;
        v2f gzM = pMB - mMB;
        v2f denS = __builtin_elementwise_fma(gxS, gxS,
                   __builtin_elementwise_fma(gyS, gyS,
                   __builtin_elementwise_fma(gzS, gzS, i2)));
        v2f denM = __builtin_elementwise_fma(gxM, gxM,
                   __builtin_elementwise_fma(gyM, gyM,
                   __builtin_elementwise_fma(gzM, gzM, i2)));
        v2f rS = vrcp(denS);
        v2f rM = vrcp(denM);
        v2f Ux = idf * __builtin_elementwise_fma(gxS, rS, gxM * rM);
        v2f Uy = idf * __builtin_elementwise_fma(gyS, rS, gyM * rM);
        v2f Uz = idf * __builtin_elementwise_fma(gzS, rS, gzM * rM);
        v2f rz = vrcp(Uz + 1e-10f);
        v2f dxz = atanv(Ux * rz);
        v2f dyz = atanv(Uy * rz);

        v2f rf = vrcp(fFz + 1e-10f);
        v2f fxz = atanv(fFx * rf);
        v2f fyz = atanv(fFy * rf);

        v2f e1 = fxz - dxz;
        v2f e2 = fyz - dyz;
        vsum = __builtin_elementwise_fma(e1, e1,
               __builtin_elementwise_fma(e2, e2, vsum));

        // rotate ring (renamed by full unroll)
        mSPx = zSPx; mSPy = zSPy; mSB = zSB; mSC = zSC;
        mMPx = zMPx; mMPy = zMPy; mMB = zMB; mMC = zMC;
        zSPx = pSPx; zSPy = pSPy; zSB = pSB; zSC = pSC;
        zMPx = pMPx; zMPy = pMPy; zMB = pMB; zMC = pMC;
        fFx = nFx; fFy = nFy; fFz = nFz;
    }

    float lsum = vsum.x + vsum.y;
    // wave shuffle reduce -> per-wave LDS slot -> one atomic per block
    #pragma unroll
    for (int o = 32; o > 0; o >>= 1)
        lsum += __shfl_down(lsum, o, 64);
    if (lane == 0)
        redbuf[wid] = lsum;
    __syncthreads();
    if (tid == 0) {
        float s = redbuf[0] + redbuf[1] + redbuf[2] + redbuf[3];
        atomicAdd(out, s * (1.0f / (float)NVOX));
    }
}

extern "C" void kernel_launch(void* const* d_in, const int* in_sizes, int n_in,
                              void* d_out, int out_size, void* d_ws, size_t ws_size,
                              hipStream_t stream) {
    const float* Mv   = (const float*)d_in[0];
    const float* Sv   = (const float*)d_in[1];
    const float* flow = (const float*)d_in[2];
    float* out = (float*)d_out;

    hipMemsetAsync(out, 0, sizeof(float), stream);

    dim3 grid(WW / TW, HH / THB, DD / TD);   // 5 x 12 x 20 = 1200 blocks
    demons_ori_kernel<<<grid, dim3(256), 0, stream>>>(Mv, Sv, flow, out);
}